// Round 8
// baseline (173.192 us; speedup 1.0000x reference)
//
#include <hip/hip_runtime.h>
#include <stdint.h>

// Linformer attention, MI355X gfx950 — 5-dispatch, KV/Q tensors algebraically eliminated.
//  Identities: KeT[b] = (We@I[b]) @ Wk^T = Se@Wk^T ; VfT[b] = Wv @ (Wf@I[b])^T = Wv@Sf^T
//              logits = I @ Me^T with Me = Se @ G^T, G = Wq^T @ Wk
//  K0: convert I->Ibf + IT (transpose), WqT, WkT, Wv/We/Wf -> bf16 (native cvt_pk)
//  K1: Se/Sf split-K=16 partials (512 blk) + G (4 blk) — 2-phase dbuf K-loop
//  K2: reduce16 -> SS = [Se(4b); Sf(4b)] bf16
//  K3: Me = Se@G^T, VfT = Wv@Sf^T (32 blk) — 2-phase dbuf K-loop
//  K4: flash: logits = Ibf@Me^T -> softmax -> P(LDS) -> Head = P@VfT^T -> f32 out

typedef unsigned short u16;
typedef __attribute__((ext_vector_type(8))) __bf16 bf16x8;
typedef __attribute__((ext_vector_type(4))) float f32x4;
typedef __attribute__((ext_vector_type(4))) unsigned short u16x4;
typedef __attribute__((ext_vector_type(8))) unsigned short u16x8;

// Native f32->bf16 (RNE): compiler emits v_cvt_pk_bf16_f32 for adjacent pairs.
__device__ __forceinline__ u16 f2bf(float f) {
  union { __bf16 h; u16 u; } v;
  v.h = (__bf16)f;
  return v.u;
}

__device__ __forceinline__ void gld_lds16(const void* g, void* l) {
  __builtin_amdgcn_global_load_lds((const __attribute__((address_space(1))) void*)g,
                                   (__attribute__((address_space(3))) void*)l, 16, 0, 0);
}

// Stage 128 rows x 64 bf16 into swizzled LDS tile (row stride 128B, byte ^= (row&7)<<4),
// bf16 source via global_load_lds with source-preswizzled column (rule 21).
__device__ __forceinline__ void stage_tile(const u16* src, long long ld, long long kb,
                                           u16* lds, int tid) {
#pragma unroll
  for (int r = 0; r < 4; ++r) {
    const int off = r * 4096 + tid * 16;
    const int row = off >> 7;
    const int colb = (off & 127) ^ ((row & 7) << 4);
    gld_lds16(src + (long long)row * ld + kb + (colb >> 1), (char*)lds + off);
  }
}

// One K=64 step of a 128x128 4-wave tile (A,B both 128B-stride swizzled LDS).
__device__ __forceinline__ void mfma_step(const u16* Alds, const u16* Blds, int lane, int wr,
                                          int wc, f32x4 (&acc)[4][4]) {
#pragma unroll
  for (int kk = 0; kk < 2; ++kk) {
    const int ko2 = (kk * 32 + (lane >> 4) * 8) * 2;
    bf16x8 a[4], b[4];
#pragma unroll
    for (int m = 0; m < 4; ++m) {
      const int ar = wr + m * 16 + (lane & 15);
      a[m] = *(const bf16x8*)((const char*)Alds + ((ar * 128 + ko2) ^ ((ar & 7) << 4)));
    }
#pragma unroll
    for (int n = 0; n < 4; ++n) {
      const int br = wc + n * 16 + (lane & 15);
      b[n] = *(const bf16x8*)((const char*)Blds + ((br * 128 + ko2) ^ ((br & 7) << 4)));
    }
#pragma unroll
    for (int m = 0; m < 4; ++m)
#pragma unroll
      for (int n = 0; n < 4; ++n)
        acc[m][n] = __builtin_amdgcn_mfma_f32_16x16x32_bf16(a[m], b[n], acc[m][n], 0, 0, 0);
  }
}

// K0: conversions + transposes.
//  [0,2048): I 64x64 tiles -> Ibf (straight) + IT (transposed)
//  [2048,2080): Wq (16) / Wk (16) 64x64 tiles -> WqT / WkT (transposed only)
//  [2080,3120): straight converts Wv|We|Wf (4096 elems/block)
__global__ __launch_bounds__(256) void k0(const float* __restrict__ I,
                                          const float* __restrict__ Wq,
                                          const float* __restrict__ Wk,
                                          const float* __restrict__ Wv,
                                          const float* __restrict__ We,
                                          const float* __restrict__ Wf,
                                          u16* __restrict__ Ibf, u16* __restrict__ IT,
                                          u16* __restrict__ WqT, u16* __restrict__ WkT,
                                          u16* __restrict__ WvB, u16* __restrict__ WeB,
                                          u16* __restrict__ WfB) {
  const int p = blockIdx.x, t = threadIdx.x;
  if (p < 2080) {
    __shared__ u16 T[4096];  // 64x64, micro-permuted for conflict-light transpose
    const float* src;
    u16 *dT, *dS;
    long long srow, scol, tld;
    if (p < 2048) {
      const int b = p >> 9, id = p & 511;
      src = I + (long long)b * 2097152;
      srow = (long long)(id >> 2) * 64;
      scol = (long long)(id & 3) * 64;
      dS = Ibf + (long long)b * 2097152;
      dT = IT + (long long)b * 2097152;
      tld = 8192;
    } else {
      const int q = p - 2048;
      src = (q < 16) ? Wq : Wk;
      const int id = q & 15;
      srow = (long long)(id >> 2) * 64;
      scol = (long long)(id & 3) * 64;
      dS = nullptr;
      dT = (q < 16) ? WqT : WkT;
      tld = 256;
    }
    const int cc = t & 15, rL = t >> 4;
#pragma unroll
    for (int i = 0; i < 4; ++i) {
      const int r = rL + 16 * i;
      f32x4 v = *(const f32x4*)(src + (srow + r) * 256 + scol + cc * 4);
      u16x4 o = {f2bf(v[0]), f2bf(v[1]), f2bf(v[2]), f2bf(v[3])};
      if (dS) *(u16x4*)(dS + (srow + r) * 256 + scol + cc * 4) = o;
      const int P = (cc + (r & 15) + 4 * (r >> 4)) & 15;  // element (r,c) at T[r*64+P*4+(c&3)]
      *(u16x4*)&T[r * 64 + P * 4] = o;
    }
    __syncthreads();
    const int dd = t >> 2, ch2 = t & 3;
    u16 buf[16];
#pragma unroll
    for (int j = 0; j < 16; ++j) {
      const int P = ((dd >> 2) + j + 4 * ch2) & 15;  // rr = ch2*16+j: rr&15=j, rr>>4=ch2
      buf[j] = T[(ch2 * 16 + j) * 64 + P * 4 + (dd & 3)];
    }
    u16* dp = dT + (scol + dd) * tld + srow + ch2 * 16;
    *(u16x8*)dp = *(u16x8*)&buf[0];
    *(u16x8*)(dp + 8) = *(u16x8*)&buf[8];
  } else {
    const long long base = (long long)(p - 2080) * 4096;
#pragma unroll
    for (int rnd = 0; rnd < 4; ++rnd) {
      const long long e = base + rnd * 1024 + t * 4;
      const float* s;
      u16* d;
      long long eo;
      if (e < 65536) { s = Wv; d = WvB; eo = e; }
      else if (e < 2162688) { s = We; d = WeB; eo = e - 65536; }
      else { s = Wf; d = WfB; eo = e - 2162688; }
      f32x4 v = *(const f32x4*)(s + eo);
      *(u16x4*)(d + eo) = u16x4{f2bf(v[0]), f2bf(v[1]), f2bf(v[2]), f2bf(v[3])};
    }
  }
}

// K1: blocks [0,512): Se/Sf split-K=16 partials; [512,516): G = WqT @ WkT^T.
// 2-phase double-buffered K-loop (T3 minimum): STAGE(next) issued before MFMA(cur),
// single __syncthreads per iter (drains vmcnt for next tile + WAR-protects buffers).
__global__ __launch_bounds__(256) void k1(const u16* __restrict__ WqT,
                                          const u16* __restrict__ WkT,
                                          const u16* __restrict__ WeB,
                                          const u16* __restrict__ WfB,
                                          const u16* __restrict__ IT,
                                          float* __restrict__ Pp, u16* __restrict__ G) {
  __shared__ u16 Alds[2][8192];
  __shared__ u16 Blds[2][8192];
  const int tid = threadIdx.x, lane = tid & 63, w = tid >> 6;
  const int wr = (w >> 1) * 64, wc = (w & 1) * 64;
  const u16 *A, *Bp;
  long long lda, k0, crow, ccol;
  int nkt;
  float* Cf = nullptr;
  u16* Cb = nullptr;
  if (blockIdx.x >= 512) {
    const int tl = blockIdx.x - 512;
    crow = (long long)(tl >> 1) * 128;
    ccol = (long long)(tl & 1) * 128;
    A = WqT + crow * 256;
    Bp = WkT + ccol * 256;
    lda = 256; k0 = 0; nkt = 4;
    Cb = G;
  } else {
    const int l = ((blockIdx.x & 7) << 6) + (blockIdx.x >> 3);  // bijective, 512 = 8*64
    const int mT = l & 1, nT = (l >> 1) & 1, s = (l >> 2) & 15, b = (l >> 6) & 3, op = l >> 8;
    A = (op ? WfB : WeB) + (long long)mT * 128 * 8192;
    Bp = IT + (long long)b * 2097152 + (long long)nT * 128 * 8192;
    lda = 8192;
    k0 = (long long)s * 512;
    nkt = 8;
    Cf = Pp + ((long long)(op * 4 + b) * 16 + s) * 65536;
    crow = (long long)mT * 128;
    ccol = (long long)nT * 128;
  }

  f32x4 acc[4][4];
#pragma unroll
  for (int m = 0; m < 4; ++m)
#pragma unroll
    for (int n = 0; n < 4; ++n) acc[m][n] = f32x4{0.f, 0.f, 0.f, 0.f};

  // prologue: stage tile 0
  stage_tile(A, lda, k0, Alds[0], tid);
  stage_tile(Bp, lda, k0, Blds[0], tid);
  __syncthreads();  // vmcnt drained: buf0 ready
  int cur = 0;
  for (int kt = 0; kt < nkt; ++kt) {
    if (kt + 1 < nkt) {  // issue next-tile loads BEFORE computing current
      stage_tile(A, lda, k0 + (kt + 1) * 64, Alds[cur ^ 1], tid);
      stage_tile(Bp, lda, k0 + (kt + 1) * 64, Blds[cur ^ 1], tid);
    }
    mfma_step(Alds[cur], Blds[cur], lane, wr, wc, acc);
    __syncthreads();  // drains prefetch + WAR-protects buf[cur] for iter kt+2
    cur ^= 1;
  }

  const int r0 = (lane >> 4) * 4, c0 = lane & 15;
#pragma unroll
  for (int m = 0; m < 4; ++m)
#pragma unroll
    for (int n = 0; n < 4; ++n) {
      const long long row = crow + wr + m * 16 + r0;
      const long long col = ccol + wc + n * 16 + c0;
#pragma unroll
      for (int j = 0; j < 4; ++j) {
        if (Cf) Cf[(row + j) * 256 + col] = acc[m][n][j];
        else Cb[(row + j) * 256 + col] = f2bf(acc[m][n][j]);
      }
    }
}

// K2: sum 16 split-K partials -> bf16. Pp: [8][16][65536] f32, SS: [8][65536] bf16.
__global__ __launch_bounds__(256) void reduce16(const float* __restrict__ P,
                                                u16* __restrict__ O) {
  const long long t = (long long)blockIdx.x * 256 + threadIdx.x;  // [0, 131072)
  const long long g = t >> 14;
  const long long e = (t & 16383) << 2;
  const float* p = P + g * 1048576 + e;
  f32x4 s = {0.f, 0.f, 0.f, 0.f};
#pragma unroll
  for (int i = 0; i < 16; ++i) s += *(const f32x4*)(p + i * 65536);
  u16x4 o = {f2bf(s[0]), f2bf(s[1]), f2bf(s[2]), f2bf(s[3])};
  *(u16x4*)(O + g * 65536 + e) = o;
}

// K3: 32 blocks: [0,16): Me[b] = Se[b]@G^T ; [16,32): VfT[b] = Wv@Sf[b]^T.
// Same 2-phase dbuf loop as K1.
__global__ __launch_bounds__(256) void k3(const u16* __restrict__ SS, const u16* __restrict__ G,
                                          const u16* __restrict__ WvB, u16* __restrict__ Me,
                                          u16* __restrict__ VfT) {
  __shared__ u16 Alds[2][8192];
  __shared__ u16 Blds[2][8192];
  const int tid = threadIdx.x, lane = tid & 63, w = tid >> 6;
  const int wr = (w >> 1) * 64, wc = (w & 1) * 64;
  const int u = blockIdx.x;
  const int path = u >> 4, b = (u >> 2) & 3, mT = (u >> 1) & 1, nT = u & 1;
  const u16 *A, *Bp;
  u16* C;
  if (path == 0) { A = SS + b * 65536; Bp = G; C = Me + b * 65536; }
  else { A = WvB; Bp = SS + (4 + b) * 65536; C = VfT + b * 65536; }
  A += (long long)mT * 128 * 256;
  Bp += (long long)nT * 128 * 256;

  f32x4 acc[4][4];
#pragma unroll
  for (int m = 0; m < 4; ++m)
#pragma unroll
    for (int n = 0; n < 4; ++n) acc[m][n] = f32x4{0.f, 0.f, 0.f, 0.f};

  stage_tile(A, 256, 0, Alds[0], tid);
  stage_tile(Bp, 256, 0, Blds[0], tid);
  __syncthreads();
  int cur = 0;
  for (int kt = 0; kt < 4; ++kt) {
    if (kt + 1 < 4) {
      stage_tile(A, 256, (kt + 1) * 64, Alds[cur ^ 1], tid);
      stage_tile(Bp, 256, (kt + 1) * 64, Blds[cur ^ 1], tid);
    }
    mfma_step(Alds[cur], Blds[cur], lane, wr, wc, acc);
    __syncthreads();
    cur ^= 1;
  }

  const int r0 = (lane >> 4) * 4, c0 = lane & 15;
#pragma unroll
  for (int m = 0; m < 4; ++m)
#pragma unroll
    for (int n = 0; n < 4; ++n) {
      const int row = mT * 128 + wr + m * 16 + r0;
      const int col = nT * 128 + wc + n * 16 + c0;
#pragma unroll
      for (int j = 0; j < 4; ++j) C[(row + j) * 256 + col] = f2bf(acc[m][n][j]);
    }
}

// Stage a 256x64 bf16 tile (src row stride 256) into Bs, source-preswizzled.
__device__ __forceinline__ void stage_bs(const u16* src, u16* Bs, int tid) {
#pragma unroll
  for (int r = 0; r < 8; ++r) {
    const int off = r * 4096 + tid * 16;
    const int row = off >> 7;
    const int colb = (off & 127) ^ ((row & 7) << 4);
    gld_lds16(src + row * 256 + (colb >> 1), (char*)Bs + off);
  }
}

// K4: per 64-row block: S = Ibf@Me^T -> softmax -> P(LDS) -> Head = P@VfT^T.
__global__ __launch_bounds__(256) void flash3(const u16* __restrict__ Q,
                                              const u16* __restrict__ KeT,
                                              const u16* __restrict__ VfT,
                                              float* __restrict__ out) {
  __shared__ u16 Qs[16384];   // 64 x 256, row stride 512B, swizzled (I rows, then P)
  __shared__ u16 Bs[16384];   // 256 x 64 (Me / VfT chunk)
  __shared__ float Ms[256];
  __shared__ float Ss[256];
  const int tid = threadIdx.x;
  const int lane = tid & 63;
  const int w = tid >> 6;
  const int wc = w * 64;
  const int l = ((blockIdx.x & 7) << 6) + (blockIdx.x >> 3);  // XCD swizzle, 512 = 8*64
  const long long R0 = (long long)l * 64;
  const int batch = (int)(R0 >> 13);
  const u16* KeTb = KeT + (long long)batch * 65536;
  const u16* VfTb = VfT + (long long)batch * 65536;
  const int r0 = (lane >> 4) * 4, c0 = lane & 15;

#pragma unroll
  for (int r = 0; r < 8; ++r) {
    const int off = r * 4096 + tid * 16;
    const int row = off >> 9;
    const int colb = (off & 511) ^ ((row & 7) << 4);
    gld_lds16(Q + (R0 + row) * 256 + (colb >> 1), (char*)Qs + off);
  }

  f32x4 acc[4][4];
#pragma unroll
  for (int m = 0; m < 4; ++m)
#pragma unroll
    for (int n = 0; n < 4; ++n) acc[m][n] = f32x4{0.f, 0.f, 0.f, 0.f};

  // ---- Phase B: S = I @ Me^T (wave w -> k cols [wc, wc+64)) ----
  for (int kc = 0; kc < 4; ++kc) {
    __syncthreads();
    stage_bs(KeTb + kc * 64, Bs, tid);
    __syncthreads();
#pragma unroll
    for (int kk = 0; kk < 2; ++kk) {
      const int ko = kk * 32 + (lane >> 4) * 8;
      bf16x8 a[4], b[4];
#pragma unroll
      for (int m = 0; m < 4; ++m) {
        const int ar = m * 16 + (lane & 15);
        a[m] = *(const bf16x8*)((const char*)Qs +
                                ((ar * 512 + (kc * 64 + ko) * 2) ^ ((ar & 7) << 4)));
      }
#pragma unroll
      for (int n = 0; n < 4; ++n) {
        const int br = wc + n * 16 + (lane & 15);
        b[n] = *(const bf16x8*)((const char*)Bs + ((br * 128 + ko * 2) ^ ((br & 7) << 4)));
      }
#pragma unroll
      for (int m = 0; m < 4; ++m)
#pragma unroll
        for (int n = 0; n < 4; ++n)
          acc[m][n] = __builtin_amdgcn_mfma_f32_16x16x32_bf16(a[m], b[n], acc[m][n], 0, 0, 0);
    }
  }

  // ---- softmax over k=256 (cols split across 4 waves) ----
  float red[4][4];
#pragma unroll
  for (int m = 0; m < 4; ++m)
#pragma unroll
    for (int j = 0; j < 4; ++j)
      red[m][j] = fmaxf(fmaxf(acc[m][0][j], acc[m][1][j]), fmaxf(acc[m][2][j], acc[m][3][j]));
#pragma unroll
  for (int d = 1; d < 16; d <<= 1)
#pragma unroll
    for (int m = 0; m < 4; ++m)
#pragma unroll
      for (int j = 0; j < 4; ++j) red[m][j] = fmaxf(red[m][j], __shfl_xor(red[m][j], d));
  if ((lane & 15) == 0) {
#pragma unroll
    for (int m = 0; m < 4; ++m)
#pragma unroll
      for (int j = 0; j < 4; ++j) Ms[(m * 16 + r0 + j) * 4 + w] = red[m][j];
  }
  __syncthreads();
  float gm[4][4];
#pragma unroll
  for (int m = 0; m < 4; ++m)
#pragma unroll
    for (int j = 0; j < 4; ++j) {
      const f32x4 t = *(const f32x4*)&Ms[(m * 16 + r0 + j) * 4];
      gm[m][j] = fmaxf(fmaxf(t[0], t[1]), fmaxf(t[2], t[3]));
    }
#pragma unroll
  for (int m = 0; m < 4; ++m)
#pragma unroll
    for (int j = 0; j < 4; ++j) {
      float s = 0.f;
#pragma unroll
      for (int n = 0; n < 4; ++n) {
        const float e = __expf((acc[m][n][j] - gm[m][j]) * 0.0625f);
        acc[m][n][j] = e;
        s += e;
      }
      red[m][j] = s;
    }
#pragma unroll
  for (int d = 1; d < 16; d <<= 1)
#pragma unroll
    for (int m = 0; m < 4; ++m)
#pragma unroll
      for (int j = 0; j < 4; ++j) red[m][j] += __shfl_xor(red[m][j], d);
  if ((lane & 15) == 0) {
#pragma unroll
    for (int m = 0; m < 4; ++m)
#pragma unroll
      for (int j = 0; j < 4; ++j) Ss[(m * 16 + r0 + j) * 4 + w] = red[m][j];
  }
  __syncthreads();
#pragma unroll
  for (int m = 0; m < 4; ++m)
#pragma unroll
    for (int j = 0; j < 4; ++j) {
      const int row = m * 16 + r0 + j;
      const f32x4 t = *(const f32x4*)&Ss[row * 4];
      const float inv = 1.0f / (t[0] + t[1] + t[2] + t[3]);
#pragma unroll
      for (int n = 0; n < 4; ++n) {
        const int col = wc + n * 16 + c0;
        *(u16*)((char*)Qs + ((row * 512 + col * 2) ^ ((row & 7) << 4))) =
            f2bf(acc[m][n][j] * inv);
      }
    }
#pragma unroll
  for (int m = 0; m < 4; ++m)
#pragma unroll
    for (int n = 0; n < 4; ++n) acc[m][n] = f32x4{0.f, 0.f, 0.f, 0.f};

  // ---- Phase C: Head = P @ VfT^T ----
  for (int kc = 0; kc < 4; ++kc) {
    __syncthreads();
    stage_bs(VfTb + kc * 64, Bs, tid);
    __syncthreads();
#pragma unroll
    for (int kk = 0; kk < 2; ++kk) {
      const int ko = kk * 32 + (lane >> 4) * 8;
      bf16x8 a[4], b[4];
#pragma unroll
      for (int m = 0; m < 4; ++m) {
        const int ar = m * 16 + (lane & 15);
        a[m] = *(const bf16x8*)((const char*)Qs +
                                ((ar * 512 + (kc * 64 + ko) * 2) ^ ((ar & 7) << 4)));
      }
#pragma unroll
      for (int n = 0; n < 4; ++n) {
        const int br = wc + n * 16 + (lane & 15);
        b[n] = *(const bf16x8*)((const char*)Bs + ((br * 128 + ko * 2) ^ ((br & 7) << 4)));
      }
#pragma unroll
      for (int m = 0; m < 4; ++m)
#pragma unroll
        for (int n = 0; n < 4; ++n)
          acc[m][n] = __builtin_amdgcn_mfma_f32_16x16x32_bf16(a[m], b[n], acc[m][n], 0, 0, 0);
    }
  }

#pragma unroll
  for (int m = 0; m < 4; ++m)
#pragma unroll
    for (int n = 0; n < 4; ++n) {
      const long long row = R0 + m * 16 + r0;
      const int col = wc + n * 16 + c0;
#pragma unroll
      for (int j = 0; j < 4; ++j) out[(row + j) * 256 + col] = acc[m][n][j];
    }
}

extern "C" void kernel_launch(void* const* d_in, const int* in_sizes, int n_in, void* d_out,
                              int out_size, void* d_ws, size_t ws_size, hipStream_t stream) {
  (void)in_sizes; (void)n_in; (void)out_size; (void)ws_size;
  const float* I  = (const float*)d_in[0];
  const float* Wq = (const float*)d_in[1];
  const float* Wk = (const float*)d_in[2];
  const float* Wv = (const float*)d_in[3];
  const float* We = (const float*)d_in[4];
  const float* Wf = (const float*)d_in[5];
  float* out = (float*)d_out;
  char* ws = (char*)d_ws;

  u16* Ibf  = (u16*)(ws + 0);          // 16.8 MB [32768][256]
  u16* IT   = (u16*)(ws + 16777216);   // 16.8 MB [4][256][8192]
  u16* WqT  = (u16*)(ws + 33554432);   // 128 KB (transposed)
  u16* WkT  = (u16*)(ws + 33685504);   // 128 KB (transposed)
  u16* WvB  = (u16*)(ws + 33816576);   // 128 KB
  u16* WeB  = (u16*)(ws + 33947648);   // 4 MB
  u16* WfB  = (u16*)(ws + 38141952);   // 4 MB
  u16* G    = (u16*)(ws + 42336256);   // 128 KB
  float* Pp = (float*)(ws + 42467328); // 33.5 MB [8][16][65536]
  u16* SS   = (u16*)(ws + 76021760);   // 1 MB [8][65536] (Se b0..3, Sf b0..3)
  u16* Me   = (u16*)(ws + 77070336);   // 512 KB [4][256][256]
  u16* VfT  = (u16*)(ws + 77594624);   // 512 KB [4][256][256]

  k0<<<3120, 256, 0, stream>>>(I, Wq, Wk, Wv, We, Wf, Ibf, IT, WqT, WkT, WvB, WeB, WfB);
  k1<<<516, 256, 0, stream>>>(WqT, WkT, WeB, WfB, IT, Pp, G);
  reduce16<<<512, 256, 0, stream>>>(Pp, SS);
  k3<<<32, 256, 0, stream>>>(SS, G, WvB, Me, VfT);
  flash3<<<512, 256, 0, stream>>>(Ibf, Me, VfT, out);
}

// Round 9
// 163.605 us; speedup vs baseline: 1.0586x; 1.0586x over previous
//
#include <hip/hip_runtime.h>
#include <stdint.h>

// Linformer attention, MI355X gfx950 — 5-dispatch, KV/Q tensors algebraically eliminated.
//  Identities: KeT[b] = (We@I[b]) @ Wk^T = Se@Wk^T ; VfT[b] = Wv @ (Wf@I[b])^T = Wv@Sf^T
//              logits = I @ Me^T with Me = Se @ G^T, G = Wq^T @ Wk
//  K0: convert I->Ibf + IT (transpose), WqT, WkT, Wv/We/Wf -> bf16 (native cvt_pk)
//  K1: Se/Sf split-K=16 partials (512 blk) + G (4 blk) — 2-phase dbuf K-loop
//  K2: reduce16 -> SS = [Se(4b); Sf(4b)] bf16
//  K3: Me = Se@G^T, VfT = Wv@Sf^T (32 blk) — 2-phase dbuf K-loop
//  K4: flash4: 256 blk x 512 thr, 128 rows/blk, kc-staggered dbuf panels.

typedef unsigned short u16;
typedef __attribute__((ext_vector_type(8))) __bf16 bf16x8;
typedef __attribute__((ext_vector_type(4))) float f32x4;
typedef __attribute__((ext_vector_type(4))) unsigned short u16x4;
typedef __attribute__((ext_vector_type(8))) unsigned short u16x8;

// Native f32->bf16 (RNE): compiler emits v_cvt_pk_bf16_f32 for adjacent pairs.
__device__ __forceinline__ u16 f2bf(float f) {
  union { __bf16 h; u16 u; } v;
  v.h = (__bf16)f;
  return v.u;
}

__device__ __forceinline__ void gld_lds16(const void* g, void* l) {
  __builtin_amdgcn_global_load_lds((const __attribute__((address_space(1))) void*)g,
                                   (__attribute__((address_space(3))) void*)l, 16, 0, 0);
}

// Stage 128 rows x 64 bf16 into swizzled LDS tile (row stride 128B, byte ^= (row&7)<<4),
// bf16 source via global_load_lds with source-preswizzled column (rule 21). 256 threads.
__device__ __forceinline__ void stage_tile(const u16* src, long long ld, long long kb,
                                           u16* lds, int tid) {
#pragma unroll
  for (int r = 0; r < 4; ++r) {
    const int off = r * 4096 + tid * 16;
    const int row = off >> 7;
    const int colb = (off & 127) ^ ((row & 7) << 4);
    gld_lds16(src + (long long)row * ld + kb + (colb >> 1), (char*)lds + off);
  }
}

// One K=64 step of a 128x128 4-wave tile (A,B both 128B-stride swizzled LDS).
__device__ __forceinline__ void mfma_step(const u16* Alds, const u16* Blds, int lane, int wr,
                                          int wc, f32x4 (&acc)[4][4]) {
#pragma unroll
  for (int kk = 0; kk < 2; ++kk) {
    const int ko2 = (kk * 32 + (lane >> 4) * 8) * 2;
    bf16x8 a[4], b[4];
#pragma unroll
    for (int m = 0; m < 4; ++m) {
      const int ar = wr + m * 16 + (lane & 15);
      a[m] = *(const bf16x8*)((const char*)Alds + ((ar * 128 + ko2) ^ ((ar & 7) << 4)));
    }
#pragma unroll
    for (int n = 0; n < 4; ++n) {
      const int br = wc + n * 16 + (lane & 15);
      b[n] = *(const bf16x8*)((const char*)Blds + ((br * 128 + ko2) ^ ((br & 7) << 4)));
    }
#pragma unroll
    for (int m = 0; m < 4; ++m)
#pragma unroll
      for (int n = 0; n < 4; ++n)
        acc[m][n] = __builtin_amdgcn_mfma_f32_16x16x32_bf16(a[m], b[n], acc[m][n], 0, 0, 0);
  }
}

// K0: conversions + transposes.
__global__ __launch_bounds__(256) void k0(const float* __restrict__ I,
                                          const float* __restrict__ Wq,
                                          const float* __restrict__ Wk,
                                          const float* __restrict__ Wv,
                                          const float* __restrict__ We,
                                          const float* __restrict__ Wf,
                                          u16* __restrict__ Ibf, u16* __restrict__ IT,
                                          u16* __restrict__ WqT, u16* __restrict__ WkT,
                                          u16* __restrict__ WvB, u16* __restrict__ WeB,
                                          u16* __restrict__ WfB) {
  const int p = blockIdx.x, t = threadIdx.x;
  if (p < 2080) {
    __shared__ u16 T[4096];  // 64x64, micro-permuted for conflict-light transpose
    const float* src;
    u16 *dT, *dS;
    long long srow, scol, tld;
    if (p < 2048) {
      const int b = p >> 9, id = p & 511;
      src = I + (long long)b * 2097152;
      srow = (long long)(id >> 2) * 64;
      scol = (long long)(id & 3) * 64;
      dS = Ibf + (long long)b * 2097152;
      dT = IT + (long long)b * 2097152;
      tld = 8192;
    } else {
      const int q = p - 2048;
      src = (q < 16) ? Wq : Wk;
      const int id = q & 15;
      srow = (long long)(id >> 2) * 64;
      scol = (long long)(id & 3) * 64;
      dS = nullptr;
      dT = (q < 16) ? WqT : WkT;
      tld = 256;
    }
    const int cc = t & 15, rL = t >> 4;
#pragma unroll
    for (int i = 0; i < 4; ++i) {
      const int r = rL + 16 * i;
      f32x4 v = *(const f32x4*)(src + (srow + r) * 256 + scol + cc * 4);
      u16x4 o = {f2bf(v[0]), f2bf(v[1]), f2bf(v[2]), f2bf(v[3])};
      if (dS) *(u16x4*)(dS + (srow + r) * 256 + scol + cc * 4) = o;
      const int P = (cc + (r & 15) + 4 * (r >> 4)) & 15;  // element (r,c) at T[r*64+P*4+(c&3)]
      *(u16x4*)&T[r * 64 + P * 4] = o;
    }
    __syncthreads();
    const int dd = t >> 2, ch2 = t & 3;
    u16 buf[16];
#pragma unroll
    for (int j = 0; j < 16; ++j) {
      const int P = ((dd >> 2) + j + 4 * ch2) & 15;  // rr = ch2*16+j: rr&15=j, rr>>4=ch2
      buf[j] = T[(ch2 * 16 + j) * 64 + P * 4 + (dd & 3)];
    }
    u16* dp = dT + (scol + dd) * tld + srow + ch2 * 16;
    *(u16x8*)dp = *(u16x8*)&buf[0];
    *(u16x8*)(dp + 8) = *(u16x8*)&buf[8];
  } else {
    const long long base = (long long)(p - 2080) * 4096;
#pragma unroll
    for (int rnd = 0; rnd < 4; ++rnd) {
      const long long e = base + rnd * 1024 + t * 4;
      const float* s;
      u16* d;
      long long eo;
      if (e < 65536) { s = Wv; d = WvB; eo = e; }
      else if (e < 2162688) { s = We; d = WeB; eo = e - 65536; }
      else { s = Wf; d = WfB; eo = e - 2162688; }
      f32x4 v = *(const f32x4*)(s + eo);
      *(u16x4*)(d + eo) = u16x4{f2bf(v[0]), f2bf(v[1]), f2bf(v[2]), f2bf(v[3])};
    }
  }
}

// K1: blocks [0,512): Se/Sf split-K=16 partials; [512,516): G = WqT @ WkT^T.
// 2-phase double-buffered K-loop.
__global__ __launch_bounds__(256) void k1(const u16* __restrict__ WqT,
                                          const u16* __restrict__ WkT,
                                          const u16* __restrict__ WeB,
                                          const u16* __restrict__ WfB,
                                          const u16* __restrict__ IT,
                                          float* __restrict__ Pp, u16* __restrict__ G) {
  __shared__ u16 Alds[2][8192];
  __shared__ u16 Blds[2][8192];
  const int tid = threadIdx.x, lane = tid & 63, w = tid >> 6;
  const int wr = (w >> 1) * 64, wc = (w & 1) * 64;
  const u16 *A, *Bp;
  long long lda, k0, crow, ccol;
  int nkt;
  float* Cf = nullptr;
  u16* Cb = nullptr;
  if (blockIdx.x >= 512) {
    const int tl = blockIdx.x - 512;
    crow = (long long)(tl >> 1) * 128;
    ccol = (long long)(tl & 1) * 128;
    A = WqT + crow * 256;
    Bp = WkT + ccol * 256;
    lda = 256; k0 = 0; nkt = 4;
    Cb = G;
  } else {
    const int l = ((blockIdx.x & 7) << 6) + (blockIdx.x >> 3);  // bijective, 512 = 8*64
    const int mT = l & 1, nT = (l >> 1) & 1, s = (l >> 2) & 15, b = (l >> 6) & 3, op = l >> 8;
    A = (op ? WfB : WeB) + (long long)mT * 128 * 8192;
    Bp = IT + (long long)b * 2097152 + (long long)nT * 128 * 8192;
    lda = 8192;
    k0 = (long long)s * 512;
    nkt = 8;
    Cf = Pp + ((long long)(op * 4 + b) * 16 + s) * 65536;
    crow = (long long)mT * 128;
    ccol = (long long)nT * 128;
  }

  f32x4 acc[4][4];
#pragma unroll
  for (int m = 0; m < 4; ++m)
#pragma unroll
    for (int n = 0; n < 4; ++n) acc[m][n] = f32x4{0.f, 0.f, 0.f, 0.f};

  stage_tile(A, lda, k0, Alds[0], tid);
  stage_tile(Bp, lda, k0, Blds[0], tid);
  __syncthreads();
  int cur = 0;
  for (int kt = 0; kt < nkt; ++kt) {
    if (kt + 1 < nkt) {
      stage_tile(A, lda, k0 + (kt + 1) * 64, Alds[cur ^ 1], tid);
      stage_tile(Bp, lda, k0 + (kt + 1) * 64, Blds[cur ^ 1], tid);
    }
    mfma_step(Alds[cur], Blds[cur], lane, wr, wc, acc);
    __syncthreads();
    cur ^= 1;
  }

  const int r0 = (lane >> 4) * 4, c0 = lane & 15;
#pragma unroll
  for (int m = 0; m < 4; ++m)
#pragma unroll
    for (int n = 0; n < 4; ++n) {
      const long long row = crow + wr + m * 16 + r0;
      const long long col = ccol + wc + n * 16 + c0;
#pragma unroll
      for (int j = 0; j < 4; ++j) {
        if (Cf) Cf[(row + j) * 256 + col] = acc[m][n][j];
        else Cb[(row + j) * 256 + col] = f2bf(acc[m][n][j]);
      }
    }
}

// K2: sum 16 split-K partials -> bf16.
__global__ __launch_bounds__(256) void reduce16(const float* __restrict__ P,
                                                u16* __restrict__ O) {
  const long long t = (long long)blockIdx.x * 256 + threadIdx.x;  // [0, 131072)
  const long long g = t >> 14;
  const long long e = (t & 16383) << 2;
  const float* p = P + g * 1048576 + e;
  f32x4 s = {0.f, 0.f, 0.f, 0.f};
#pragma unroll
  for (int i = 0; i < 16; ++i) s += *(const f32x4*)(p + i * 65536);
  u16x4 o = {f2bf(s[0]), f2bf(s[1]), f2bf(s[2]), f2bf(s[3])};
  *(u16x4*)(O + g * 65536 + e) = o;
}

// K3: 32 blocks: [0,16): Me[b] = Se[b]@G^T ; [16,32): VfT[b] = Wv@Sf[b]^T.
__global__ __launch_bounds__(256) void k3(const u16* __restrict__ SS, const u16* __restrict__ G,
                                          const u16* __restrict__ WvB, u16* __restrict__ Me,
                                          u16* __restrict__ VfT) {
  __shared__ u16 Alds[2][8192];
  __shared__ u16 Blds[2][8192];
  const int tid = threadIdx.x, lane = tid & 63, w = tid >> 6;
  const int wr = (w >> 1) * 64, wc = (w & 1) * 64;
  const int u = blockIdx.x;
  const int path = u >> 4, b = (u >> 2) & 3, mT = (u >> 1) & 1, nT = u & 1;
  const u16 *A, *Bp;
  u16* C;
  if (path == 0) { A = SS + b * 65536; Bp = G; C = Me + b * 65536; }
  else { A = WvB; Bp = SS + (4 + b) * 65536; C = VfT + b * 65536; }
  A += (long long)mT * 128 * 256;
  Bp += (long long)nT * 128 * 256;

  f32x4 acc[4][4];
#pragma unroll
  for (int m = 0; m < 4; ++m)
#pragma unroll
    for (int n = 0; n < 4; ++n) acc[m][n] = f32x4{0.f, 0.f, 0.f, 0.f};

  stage_tile(A, 256, 0, Alds[0], tid);
  stage_tile(Bp, 256, 0, Blds[0], tid);
  __syncthreads();
  int cur = 0;
  for (int kt = 0; kt < 4; ++kt) {
    if (kt + 1 < 4) {
      stage_tile(A, 256, (kt + 1) * 64, Alds[cur ^ 1], tid);
      stage_tile(Bp, 256, (kt + 1) * 64, Blds[cur ^ 1], tid);
    }
    mfma_step(Alds[cur], Blds[cur], lane, wr, wc, acc);
    __syncthreads();
    cur ^= 1;
  }

  const int r0 = (lane >> 4) * 4, c0 = lane & 15;
#pragma unroll
  for (int m = 0; m < 4; ++m)
#pragma unroll
    for (int n = 0; n < 4; ++n) {
      const int row = mT * 128 + wr + m * 16 + r0;
      const int col = nT * 128 + wc + n * 16 + c0;
#pragma unroll
      for (int j = 0; j < 4; ++j) C[(row + j) * 256 + col] = f2bf(acc[m][n][j]);
    }
}

// ---- K4: flash4 — 512 threads, 128 rows/block, staggered dbuf panels ----

// Stage 256x64 panel (src row stride 256) with 512 threads into 32KB swizzled tile.
__device__ __forceinline__ void stage_p(const u16* src, u16* dst, int tid) {
#pragma unroll
  for (int r = 0; r < 4; ++r) {
    const int off = r * 8192 + tid * 16;
    const int row = off >> 7;
    const int colb = (off & 127) ^ ((row & 7) << 4);
    gld_lds16(src + row * 256 + (colb >> 1), (char*)dst + off);
  }
}

// One kc-slice (contraction cols [kc*64,kc*64+64)): A from Qs (stride 512B), B from panel.
__device__ __forceinline__ void mfma8(const u16* Qs, const u16* Bsb, int lane, int wr, int wc,
                                      int kc, f32x4 (&acc)[4][4]) {
#pragma unroll
  for (int kk = 0; kk < 2; ++kk) {
    const int ko = kk * 32 + (lane >> 4) * 8;
    bf16x8 a[4], b[4];
#pragma unroll
    for (int m = 0; m < 4; ++m) {
      const int ar = wr + m * 16 + (lane & 15);
      a[m] = *(const bf16x8*)((const char*)Qs +
                              ((ar * 512 + (kc * 64 + ko) * 2) ^ ((ar & 7) << 4)));
    }
#pragma unroll
    for (int n = 0; n < 4; ++n) {
      const int br = wc + n * 16 + (lane & 15);
      b[n] = *(const bf16x8*)((const char*)Bsb + ((br * 128 + ko * 2) ^ ((br & 7) << 4)));
    }
#pragma unroll
    for (int m = 0; m < 4; ++m)
#pragma unroll
      for (int n = 0; n < 4; ++n)
        acc[m][n] = __builtin_amdgcn_mfma_f32_16x16x32_bf16(a[m], b[n], acc[m][n], 0, 0, 0);
  }
}

__global__ __launch_bounds__(512) void flash4(const u16* __restrict__ Q,
                                              const u16* __restrict__ Me,
                                              const u16* __restrict__ VfT,
                                              float* __restrict__ out) {
  __shared__ u16 Qs[32768];      // 128 x 256, stride 512B, swizzled (I rows, then P)
  __shared__ u16 Bs[2][16384];   // dbuf 256x64 panels
  __shared__ float Ms[512];      // [row][wcg]
  __shared__ float Ss[512];
  const int tid = threadIdx.x;
  const int lane = tid & 63;
  const int w = tid >> 6;
  const int wr = (w & 1) * 64;
  const int wcg = w >> 1;
  const int wc = wcg * 64;
  const int l = ((blockIdx.x & 7) << 5) + (blockIdx.x >> 3);  // XCD swizzle, 256 = 8*32
  const long long R0 = (long long)l * 128;
  const int batch = l >> 6;
  const int kc0 = l & 3;  // stagger: de-synchronize panel reads across blocks
  const u16* Meb = Me + (long long)batch * 65536;
  const u16* Vfb = VfT + (long long)batch * 65536;
  const int r0 = (lane >> 4) * 4, c0 = lane & 15;

  // stage Qs (128 rows x 256, 64KB) + first Me panel
#pragma unroll
  for (int r = 0; r < 8; ++r) {
    const int off = r * 8192 + tid * 16;
    const int row = off >> 9;
    const int colb = (off & 511) ^ ((row & 7) << 4);
    gld_lds16(Q + (R0 + row) * 256 + (colb >> 1), (char*)Qs + off);
  }
  stage_p(Meb + kc0 * 64, Bs[0], tid);

  f32x4 acc[4][4];
#pragma unroll
  for (int m = 0; m < 4; ++m)
#pragma unroll
    for (int n = 0; n < 4; ++n) acc[m][n] = f32x4{0.f, 0.f, 0.f, 0.f};

  // ---- Phase B: S = Qs @ Me^T (acc over kc in staggered order) ----
  int cur = 0;
#pragma unroll
  for (int i = 0; i < 4; ++i) {
    __syncthreads();  // drains stage for Bs[cur] (i=0: +Qs); WAR-safe (see R8 notes)
    if (i < 3) stage_p(Meb + (((kc0 + i + 1) & 3)) * 64, Bs[cur ^ 1], tid);
    mfma8(Qs, Bs[cur], lane, wr, wc, (kc0 + i) & 3, acc);
    cur ^= 1;
  }
  // after 4 iters cur == 0; Bs[1] was last-read, Bs[0] free.

  // ---- softmax over k=256 (k split across wcg groups) ----
  float red[4][4];
#pragma unroll
  for (int m = 0; m < 4; ++m)
#pragma unroll
    for (int j = 0; j < 4; ++j)
      red[m][j] = fmaxf(fmaxf(acc[m][0][j], acc[m][1][j]), fmaxf(acc[m][2][j], acc[m][3][j]));
#pragma unroll
  for (int d = 1; d < 16; d <<= 1)
#pragma unroll
    for (int m = 0; m < 4; ++m)
#pragma unroll
      for (int j = 0; j < 4; ++j) red[m][j] = fmaxf(red[m][j], __shfl_xor(red[m][j], d));
  // overlap: issue Phase C prologue stage now (Bs[0] free; lands during softmax)
  stage_p(Vfb + kc0 * 64, Bs[0], tid);
  if ((lane & 15) == 0) {
#pragma unroll
    for (int m = 0; m < 4; ++m)
#pragma unroll
      for (int j = 0; j < 4; ++j) Ms[(wr + m * 16 + r0 + j) * 4 + wcg] = red[m][j];
  }
  __syncthreads();
  float gm[4][4];
#pragma unroll
  for (int m = 0; m < 4; ++m)
#pragma unroll
    for (int j = 0; j < 4; ++j) {
      const f32x4 t = *(const f32x4*)&Ms[(wr + m * 16 + r0 + j) * 4];
      gm[m][j] = fmaxf(fmaxf(t[0], t[1]), fmaxf(t[2], t[3]));
    }
#pragma unroll
  for (int m = 0; m < 4; ++m)
#pragma unroll
    for (int j = 0; j < 4; ++j) {
      float s = 0.f;
#pragma unroll
      for (int n = 0; n < 4; ++n) {
        const float e = __expf((acc[m][n][j] - gm[m][j]) * 0.0625f);
        acc[m][n][j] = e;
        s += e;
      }
      red[m][j] = s;
    }
#pragma unroll
  for (int d = 1; d < 16; d <<= 1)
#pragma unroll
    for (int m = 0; m < 4; ++m)
#pragma unroll
      for (int j = 0; j < 4; ++j) red[m][j] += __shfl_xor(red[m][j], d);
  if ((lane & 15) == 0) {
#pragma unroll
    for (int m = 0; m < 4; ++m)
#pragma unroll
      for (int j = 0; j < 4; ++j) Ss[(wr + m * 16 + r0 + j) * 4 + wcg] = red[m][j];
  }
  __syncthreads();  // Ss visible; all Phase-B Qs reads done -> safe to overwrite with P
#pragma unroll
  for (int m = 0; m < 4; ++m)
#pragma unroll
    for (int j = 0; j < 4; ++j) {
      const int row = wr + m * 16 + r0 + j;
      const f32x4 t = *(const f32x4*)&Ss[row * 4];
      const float inv = 1.0f / (t[0] + t[1] + t[2] + t[3]);
#pragma unroll
      for (int n = 0; n < 4; ++n) {
        const int col = wc + n * 16 + c0;
        *(u16*)((char*)Qs + ((row * 512 + col * 2) ^ ((row & 7) << 4))) =
            f2bf(acc[m][n][j] * inv);
      }
    }
#pragma unroll
  for (int m = 0; m < 4; ++m)
#pragma unroll
    for (int n = 0; n < 4; ++n) acc[m][n] = f32x4{0.f, 0.f, 0.f, 0.f};

  // ---- Phase C: Head = P @ VfT^T (staggered dbuf) ----
  cur = 0;
#pragma unroll
  for (int i = 0; i < 4; ++i) {
    __syncthreads();  // i=0: drains VfT prologue + publishes P writes
    if (i < 3) stage_p(Vfb + (((kc0 + i + 1) & 3)) * 64, Bs[cur ^ 1], tid);
    mfma8(Qs, Bs[cur], lane, wr, wc, (kc0 + i) & 3, acc);
    cur ^= 1;
  }

  // ---- store f32 out ----
#pragma unroll
  for (int m = 0; m < 4; ++m)
#pragma unroll
    for (int n = 0; n < 4; ++n) {
      const long long row = R0 + wr + m * 16 + r0;
      const int col = wc + n * 16 + c0;
#pragma unroll
      for (int j = 0; j < 4; ++j) out[(row + j) * 256 + col] = acc[m][n][j];
    }
}

extern "C" void kernel_launch(void* const* d_in, const int* in_sizes, int n_in, void* d_out,
                              int out_size, void* d_ws, size_t ws_size, hipStream_t stream) {
  (void)in_sizes; (void)n_in; (void)out_size; (void)ws_size;
  const float* I  = (const float*)d_in[0];
  const float* Wq = (const float*)d_in[1];
  const float* Wk = (const float*)d_in[2];
  const float* Wv = (const float*)d_in[3];
  const float* We = (const float*)d_in[4];
  const float* Wf = (const float*)d_in[5];
  float* out = (float*)d_out;
  char* ws = (char*)d_ws;

  u16* Ibf  = (u16*)(ws + 0);          // 16.8 MB [32768][256]
  u16* IT   = (u16*)(ws + 16777216);   // 16.8 MB [4][256][8192]
  u16* WqT  = (u16*)(ws + 33554432);   // 128 KB (transposed)
  u16* WkT  = (u16*)(ws + 33685504);   // 128 KB (transposed)
  u16* WvB  = (u16*)(ws + 33816576);   // 128 KB
  u16* WeB  = (u16*)(ws + 33947648);   // 4 MB
  u16* WfB  = (u16*)(ws + 38141952);   // 4 MB
  u16* G    = (u16*)(ws + 42336256);   // 128 KB
  float* Pp = (float*)(ws + 42467328); // 33.5 MB [8][16][65536]
  u16* SS   = (u16*)(ws + 76021760);   // 1 MB [8][65536] (Se b0..3, Sf b0..3)
  u16* Me   = (u16*)(ws + 77070336);   // 512 KB [4][256][256]
  u16* VfT  = (u16*)(ws + 77594624);   // 512 KB [4][256][256]

  k0<<<3120, 256, 0, stream>>>(I, Wq, Wk, Wv, We, Wf, Ibf, IT, WqT, WkT, WvB, WeB, WfB);
  k1<<<516, 256, 0, stream>>>(WqT, WkT, WeB, WfB, IT, Pp, G);
  reduce16<<<512, 256, 0, stream>>>(Pp, SS);
  k3<<<32, 256, 0, stream>>>(SS, G, WvB, Me, VfT);
  flash4<<<256, 512, 0, stream>>>(Ibf, Me, VfT, out);
}

// Round 10
// 162.858 us; speedup vs baseline: 1.0635x; 1.0046x over previous
//
#include <hip/hip_runtime.h>
#include <stdint.h>

// Linformer attention, MI355X gfx950 — 5-dispatch, KV/Q tensors algebraically eliminated.
//  Identities: KeT[b] = (We@I[b]) @ Wk^T = Se@Wk^T ; VfT[b] = Wv @ (Wf@I[b])^T = Wv@Sf^T
//              logits = I @ Me^T with Me = Se @ G^T, G = Wq^T @ Wk
//  K0: convert I->Ibf + IT (transpose), WqT, WkT, Wv/We/Wf -> bf16 (native cvt_pk)
//  K1: Se/Sf split-K=16 partials (512 blk) + G (4 blk) — 2-phase dbuf K-loop
//  K2: reduce16 -> SS = [Se(4b); Sf(4b)] bf16
//  K3: Me = Se@G^T, VfT = Wv@Sf^T (32 blk) — 2-phase dbuf K-loop
//  K4: flash6: 512 blk x 256 thr, 64 rows/blk, wave-local strip staging, 4 barriers total.

typedef unsigned short u16;
typedef __attribute__((ext_vector_type(8))) __bf16 bf16x8;
typedef __attribute__((ext_vector_type(4))) float f32x4;
typedef __attribute__((ext_vector_type(4))) unsigned short u16x4;
typedef __attribute__((ext_vector_type(8))) unsigned short u16x8;

// Native f32->bf16 (RNE): compiler emits v_cvt_pk_bf16_f32 for adjacent pairs.
__device__ __forceinline__ u16 f2bf(float f) {
  union { __bf16 h; u16 u; } v;
  v.h = (__bf16)f;
  return v.u;
}

__device__ __forceinline__ void gld_lds16(const void* g, void* l) {
  __builtin_amdgcn_global_load_lds((const __attribute__((address_space(1))) void*)g,
                                   (__attribute__((address_space(3))) void*)l, 16, 0, 0);
}

// Stage 128 rows x 64 bf16 into swizzled LDS tile (row stride 128B, byte ^= (row&7)<<4),
// bf16 source via global_load_lds with source-preswizzled column (rule 21). 256 threads.
__device__ __forceinline__ void stage_tile(const u16* src, long long ld, long long kb,
                                           u16* lds, int tid) {
#pragma unroll
  for (int r = 0; r < 4; ++r) {
    const int off = r * 4096 + tid * 16;
    const int row = off >> 7;
    const int colb = (off & 127) ^ ((row & 7) << 4);
    gld_lds16(src + (long long)row * ld + kb + (colb >> 1), (char*)lds + off);
  }
}

// One K=64 step of a 128x128 4-wave tile (A,B both 128B-stride swizzled LDS).
__device__ __forceinline__ void mfma_step(const u16* Alds, const u16* Blds, int lane, int wr,
                                          int wc, f32x4 (&acc)[4][4]) {
#pragma unroll
  for (int kk = 0; kk < 2; ++kk) {
    const int ko2 = (kk * 32 + (lane >> 4) * 8) * 2;
    bf16x8 a[4], b[4];
#pragma unroll
    for (int m = 0; m < 4; ++m) {
      const int ar = wr + m * 16 + (lane & 15);
      a[m] = *(const bf16x8*)((const char*)Alds + ((ar * 128 + ko2) ^ ((ar & 7) << 4)));
    }
#pragma unroll
    for (int n = 0; n < 4; ++n) {
      const int br = wc + n * 16 + (lane & 15);
      b[n] = *(const bf16x8*)((const char*)Blds + ((br * 128 + ko2) ^ ((br & 7) << 4)));
    }
#pragma unroll
    for (int m = 0; m < 4; ++m)
#pragma unroll
      for (int n = 0; n < 4; ++n)
        acc[m][n] = __builtin_amdgcn_mfma_f32_16x16x32_bf16(a[m], b[n], acc[m][n], 0, 0, 0);
  }
}

// K0: conversions + transposes.
__global__ __launch_bounds__(256) void k0(const float* __restrict__ I,
                                          const float* __restrict__ Wq,
                                          const float* __restrict__ Wk,
                                          const float* __restrict__ Wv,
                                          const float* __restrict__ We,
                                          const float* __restrict__ Wf,
                                          u16* __restrict__ Ibf, u16* __restrict__ IT,
                                          u16* __restrict__ WqT, u16* __restrict__ WkT,
                                          u16* __restrict__ WvB, u16* __restrict__ WeB,
                                          u16* __restrict__ WfB) {
  const int p = blockIdx.x, t = threadIdx.x;
  if (p < 2080) {
    __shared__ u16 T[4096];  // 64x64, micro-permuted for conflict-light transpose
    const float* src;
    u16 *dT, *dS;
    long long srow, scol, tld;
    if (p < 2048) {
      const int b = p >> 9, id = p & 511;
      src = I + (long long)b * 2097152;
      srow = (long long)(id >> 2) * 64;
      scol = (long long)(id & 3) * 64;
      dS = Ibf + (long long)b * 2097152;
      dT = IT + (long long)b * 2097152;
      tld = 8192;
    } else {
      const int q = p - 2048;
      src = (q < 16) ? Wq : Wk;
      const int id = q & 15;
      srow = (long long)(id >> 2) * 64;
      scol = (long long)(id & 3) * 64;
      dS = nullptr;
      dT = (q < 16) ? WqT : WkT;
      tld = 256;
    }
    const int cc = t & 15, rL = t >> 4;
#pragma unroll
    for (int i = 0; i < 4; ++i) {
      const int r = rL + 16 * i;
      f32x4 v = *(const f32x4*)(src + (srow + r) * 256 + scol + cc * 4);
      u16x4 o = {f2bf(v[0]), f2bf(v[1]), f2bf(v[2]), f2bf(v[3])};
      if (dS) *(u16x4*)(dS + (srow + r) * 256 + scol + cc * 4) = o;
      const int P = (cc + (r & 15) + 4 * (r >> 4)) & 15;  // element (r,c) at T[r*64+P*4+(c&3)]
      *(u16x4*)&T[r * 64 + P * 4] = o;
    }
    __syncthreads();
    const int dd = t >> 2, ch2 = t & 3;
    u16 buf[16];
#pragma unroll
    for (int j = 0; j < 16; ++j) {
      const int P = ((dd >> 2) + j + 4 * ch2) & 15;  // rr = ch2*16+j: rr&15=j, rr>>4=ch2
      buf[j] = T[(ch2 * 16 + j) * 64 + P * 4 + (dd & 3)];
    }
    u16* dp = dT + (scol + dd) * tld + srow + ch2 * 16;
    *(u16x8*)dp = *(u16x8*)&buf[0];
    *(u16x8*)(dp + 8) = *(u16x8*)&buf[8];
  } else {
    const long long base = (long long)(p - 2080) * 4096;
#pragma unroll
    for (int rnd = 0; rnd < 4; ++rnd) {
      const long long e = base + rnd * 1024 + t * 4;
      const float* s;
      u16* d;
      long long eo;
      if (e < 65536) { s = Wv; d = WvB; eo = e; }
      else if (e < 2162688) { s = We; d = WeB; eo = e - 65536; }
      else { s = Wf; d = WfB; eo = e - 2162688; }
      f32x4 v = *(const f32x4*)(s + eo);
      *(u16x4*)(d + eo) = u16x4{f2bf(v[0]), f2bf(v[1]), f2bf(v[2]), f2bf(v[3])};
    }
  }
}

// K1: blocks [0,512): Se/Sf split-K=16 partials; [512,516): G = WqT @ WkT^T.
// 2-phase double-buffered K-loop.
__global__ __launch_bounds__(256) void k1(const u16* __restrict__ WqT,
                                          const u16* __restrict__ WkT,
                                          const u16* __restrict__ WeB,
                                          const u16* __restrict__ WfB,
                                          const u16* __restrict__ IT,
                                          float* __restrict__ Pp, u16* __restrict__ G) {
  __shared__ u16 Alds[2][8192];
  __shared__ u16 Blds[2][8192];
  const int tid = threadIdx.x, lane = tid & 63, w = tid >> 6;
  const int wr = (w >> 1) * 64, wc = (w & 1) * 64;
  const u16 *A, *Bp;
  long long lda, k0, crow, ccol;
  int nkt;
  float* Cf = nullptr;
  u16* Cb = nullptr;
  if (blockIdx.x >= 512) {
    const int tl = blockIdx.x - 512;
    crow = (long long)(tl >> 1) * 128;
    ccol = (long long)(tl & 1) * 128;
    A = WqT + crow * 256;
    Bp = WkT + ccol * 256;
    lda = 256; k0 = 0; nkt = 4;
    Cb = G;
  } else {
    const int l = ((blockIdx.x & 7) << 6) + (blockIdx.x >> 3);  // bijective, 512 = 8*64
    const int mT = l & 1, nT = (l >> 1) & 1, s = (l >> 2) & 15, b = (l >> 6) & 3, op = l >> 8;
    A = (op ? WfB : WeB) + (long long)mT * 128 * 8192;
    Bp = IT + (long long)b * 2097152 + (long long)nT * 128 * 8192;
    lda = 8192;
    k0 = (long long)s * 512;
    nkt = 8;
    Cf = Pp + ((long long)(op * 4 + b) * 16 + s) * 65536;
    crow = (long long)mT * 128;
    ccol = (long long)nT * 128;
  }

  f32x4 acc[4][4];
#pragma unroll
  for (int m = 0; m < 4; ++m)
#pragma unroll
    for (int n = 0; n < 4; ++n) acc[m][n] = f32x4{0.f, 0.f, 0.f, 0.f};

  stage_tile(A, lda, k0, Alds[0], tid);
  stage_tile(Bp, lda, k0, Blds[0], tid);
  __syncthreads();
  int cur = 0;
  for (int kt = 0; kt < nkt; ++kt) {
    if (kt + 1 < nkt) {
      stage_tile(A, lda, k0 + (kt + 1) * 64, Alds[cur ^ 1], tid);
      stage_tile(Bp, lda, k0 + (kt + 1) * 64, Blds[cur ^ 1], tid);
    }
    mfma_step(Alds[cur], Blds[cur], lane, wr, wc, acc);
    __syncthreads();
    cur ^= 1;
  }

  const int r0 = (lane >> 4) * 4, c0 = lane & 15;
#pragma unroll
  for (int m = 0; m < 4; ++m)
#pragma unroll
    for (int n = 0; n < 4; ++n) {
      const long long row = crow + wr + m * 16 + r0;
      const long long col = ccol + wc + n * 16 + c0;
#pragma unroll
      for (int j = 0; j < 4; ++j) {
        if (Cf) Cf[(row + j) * 256 + col] = acc[m][n][j];
        else Cb[(row + j) * 256 + col] = f2bf(acc[m][n][j]);
      }
    }
}

// K2: sum 16 split-K partials -> bf16.
__global__ __launch_bounds__(256) void reduce16(const float* __restrict__ P,
                                                u16* __restrict__ O) {
  const long long t = (long long)blockIdx.x * 256 + threadIdx.x;  // [0, 131072)
  const long long g = t >> 14;
  const long long e = (t & 16383) << 2;
  const float* p = P + g * 1048576 + e;
  f32x4 s = {0.f, 0.f, 0.f, 0.f};
#pragma unroll
  for (int i = 0; i < 16; ++i) s += *(const f32x4*)(p + i * 65536);
  u16x4 o = {f2bf(s[0]), f2bf(s[1]), f2bf(s[2]), f2bf(s[3])};
  *(u16x4*)(O + g * 65536 + e) = o;
}

// K3: 32 blocks: [0,16): Me[b] = Se[b]@G^T ; [16,32): VfT[b] = Wv@Sf[b]^T.
__global__ __launch_bounds__(256) void k3(const u16* __restrict__ SS, const u16* __restrict__ G,
                                          const u16* __restrict__ WvB, u16* __restrict__ Me,
                                          u16* __restrict__ VfT) {
  __shared__ u16 Alds[2][8192];
  __shared__ u16 Blds[2][8192];
  const int tid = threadIdx.x, lane = tid & 63, w = tid >> 6;
  const int wr = (w >> 1) * 64, wc = (w & 1) * 64;
  const int u = blockIdx.x;
  const int path = u >> 4, b = (u >> 2) & 3, mT = (u >> 1) & 1, nT = u & 1;
  const u16 *A, *Bp;
  u16* C;
  if (path == 0) { A = SS + b * 65536; Bp = G; C = Me + b * 65536; }
  else { A = WvB; Bp = SS + (4 + b) * 65536; C = VfT + b * 65536; }
  A += (long long)mT * 128 * 256;
  Bp += (long long)nT * 128 * 256;

  f32x4 acc[4][4];
#pragma unroll
  for (int m = 0; m < 4; ++m)
#pragma unroll
    for (int n = 0; n < 4; ++n) acc[m][n] = f32x4{0.f, 0.f, 0.f, 0.f};

  stage_tile(A, 256, 0, Alds[0], tid);
  stage_tile(Bp, 256, 0, Blds[0], tid);
  __syncthreads();
  int cur = 0;
  for (int kt = 0; kt < 4; ++kt) {
    if (kt + 1 < 4) {
      stage_tile(A, 256, (kt + 1) * 64, Alds[cur ^ 1], tid);
      stage_tile(Bp, 256, (kt + 1) * 64, Blds[cur ^ 1], tid);
    }
    mfma_step(Alds[cur], Blds[cur], lane, wr, wc, acc);
    __syncthreads();
    cur ^= 1;
  }

  const int r0 = (lane >> 4) * 4, c0 = lane & 15;
#pragma unroll
  for (int m = 0; m < 4; ++m)
#pragma unroll
    for (int n = 0; n < 4; ++n) {
      const int row = mT * 128 + wr + m * 16 + r0;
      const int col = nT * 128 + wc + n * 16 + c0;
#pragma unroll
      for (int j = 0; j < 4; ++j) C[(row + j) * 256 + col] = f2bf(acc[m][n][j]);
    }
}

// ---- K4: flash6 — 512 blk x 256 thr, 64 rows, wave-local strip staging ----
// Wave w owns output cols [w*64, w*64+64) (k in Phase B, d in Phase C) and stages its own
// 64x64 B-strip per contraction chunk with wave-local gld_lds + vmcnt(0) (no barriers in
// the MFMA loops). Only Qs stage / softmax / P-publish use __syncthreads (4 total).
__global__ __launch_bounds__(256) void flash6(const u16* __restrict__ Q,
                                              const u16* __restrict__ Me,
                                              const u16* __restrict__ VfT,
                                              float* __restrict__ out) {
  __shared__ u16 Qs[16384];      // 64 x 256, stride 512B, swizzled (I rows, then P)
  __shared__ u16 Bst[4][4096];   // per-wave 64x64 strip, stride 128B, swizzled
  __shared__ float Ms[256];      // [row][wave]
  __shared__ float Ss[256];
  const int tid = threadIdx.x;
  const int lane = tid & 63;
  const int w = tid >> 6;
  const int wc = w * 64;
  const int l = ((blockIdx.x & 7) << 6) + (blockIdx.x >> 3);  // XCD swizzle, 512 = 8*64
  const long long R0 = (long long)l * 64;
  const int batch = (int)(R0 >> 13);
  const int kc0 = l & 3;  // stagger chunk order across blocks
  const u16* Meb = Me + (long long)batch * 65536;
  const u16* Vfb = VfT + (long long)batch * 65536;
  const int r0 = (lane >> 4) * 4, c0 = lane & 15;

  // cooperative Qs stage: 64 rows x 256 (32KB), swizzled via source col
#pragma unroll
  for (int r = 0; r < 8; ++r) {
    const int off = r * 4096 + tid * 16;
    const int row = off >> 9;
    const int colb = (off & 511) ^ ((row & 7) << 4);
    gld_lds16(Q + (R0 + row) * 256 + (colb >> 1), (char*)Qs + off);
  }
  __syncthreads();  // Qs ready (vmcnt drained before barrier)

  // wave-local strip stage: rows [wc, wc+64) of src, cols [kc*64, kc*64+64)
  auto stage_strip = [&](const u16* base, int kc) {
#pragma unroll
    for (int r = 0; r < 8; ++r) {
      const int off = r * 1024 + lane * 16;
      const int row = off >> 7;
      const int colb = (off & 127) ^ ((row & 7) << 4);
      gld_lds16(base + (wc + row) * 256 + kc * 64 + (colb >> 1), (char*)Bst[w] + off);
    }
    asm volatile("s_waitcnt vmcnt(0)" ::: "memory");
    __builtin_amdgcn_sched_barrier(0);
  };

  f32x4 acc[4][4];
#pragma unroll
  for (int m = 0; m < 4; ++m)
#pragma unroll
    for (int n = 0; n < 4; ++n) acc[m][n] = f32x4{0.f, 0.f, 0.f, 0.f};

  // ---- Phase B: S = Q @ Me^T (contraction over d in 4 staggered chunks) ----
  for (int i = 0; i < 4; ++i) {
    const int kc = (kc0 + i) & 3;
    stage_strip(Meb, kc);
#pragma unroll
    for (int kk = 0; kk < 2; ++kk) {
      const int ko = kk * 32 + (lane >> 4) * 8;
      bf16x8 a[4], b[4];
#pragma unroll
      for (int m = 0; m < 4; ++m) {
        const int ar = m * 16 + (lane & 15);
        a[m] = *(const bf16x8*)((const char*)Qs +
                                ((ar * 512 + (kc * 64 + ko) * 2) ^ ((ar & 7) << 4)));
      }
#pragma unroll
      for (int n = 0; n < 4; ++n) {
        const int br = n * 16 + (lane & 15);
        b[n] = *(const bf16x8*)((const char*)Bst[w] + ((br * 128 + ko * 2) ^ ((br & 7) << 4)));
      }
#pragma unroll
      for (int m = 0; m < 4; ++m)
#pragma unroll
        for (int n = 0; n < 4; ++n)
          acc[m][n] = __builtin_amdgcn_mfma_f32_16x16x32_bf16(a[m], b[n], acc[m][n], 0, 0, 0);
    }
  }

  // ---- softmax over k=256 (k split across 4 waves) ----
  float red[4][4];
#pragma unroll
  for (int m = 0; m < 4; ++m)
#pragma unroll
    for (int j = 0; j < 4; ++j)
      red[m][j] = fmaxf(fmaxf(acc[m][0][j], acc[m][1][j]), fmaxf(acc[m][2][j], acc[m][3][j]));
#pragma unroll
  for (int d = 1; d < 16; d <<= 1)
#pragma unroll
    for (int m = 0; m < 4; ++m)
#pragma unroll
      for (int j = 0; j < 4; ++j) red[m][j] = fmaxf(red[m][j], __shfl_xor(red[m][j], d));
  if ((lane & 15) == 0) {
#pragma unroll
    for (int m = 0; m < 4; ++m)
#pragma unroll
      for (int j = 0; j < 4; ++j) Ms[(m * 16 + r0 + j) * 4 + w] = red[m][j];
  }
  __syncthreads();  // Ms visible; all waves past Phase B (Qs now overwritable)
  float gm[4][4];
#pragma unroll
  for (int m = 0; m < 4; ++m)
#pragma unroll
    for (int j = 0; j < 4; ++j) {
      const f32x4 t = *(const f32x4*)&Ms[(m * 16 + r0 + j) * 4];
      gm[m][j] = fmaxf(fmaxf(t[0], t[1]), fmaxf(t[2], t[3]));
    }
#pragma unroll
  for (int m = 0; m < 4; ++m)
#pragma unroll
    for (int j = 0; j < 4; ++j) {
      float s = 0.f;
#pragma unroll
      for (int n = 0; n < 4; ++n) {
        const float e = __expf((acc[m][n][j] - gm[m][j]) * 0.0625f);
        acc[m][n][j] = e;
        s += e;
      }
      red[m][j] = s;
    }
#pragma unroll
  for (int d = 1; d < 16; d <<= 1)
#pragma unroll
    for (int m = 0; m < 4; ++m)
#pragma unroll
      for (int j = 0; j < 4; ++j) red[m][j] += __shfl_xor(red[m][j], d);
  if ((lane & 15) == 0) {
#pragma unroll
    for (int m = 0; m < 4; ++m)
#pragma unroll
      for (int j = 0; j < 4; ++j) Ss[(m * 16 + r0 + j) * 4 + w] = red[m][j];
  }
  __syncthreads();  // Ss visible
  // P -> Qs (bf16, scaled by 1/sum); wave writes its k-col stripe
#pragma unroll
  for (int m = 0; m < 4; ++m)
#pragma unroll
    for (int j = 0; j < 4; ++j) {
      const int row = m * 16 + r0 + j;
      const f32x4 t = *(const f32x4*)&Ss[row * 4];
      const float inv = 1.0f / (t[0] + t[1] + t[2] + t[3]);
#pragma unroll
      for (int n = 0; n < 4; ++n) {
        const int col = wc + n * 16 + c0;
        *(u16*)((char*)Qs + ((row * 512 + col * 2) ^ ((row & 7) << 4))) =
            f2bf(acc[m][n][j] * inv);
      }
    }
#pragma unroll
  for (int m = 0; m < 4; ++m)
#pragma unroll
    for (int n = 0; n < 4; ++n) acc[m][n] = f32x4{0.f, 0.f, 0.f, 0.f};
  __syncthreads();  // publish P stripes (cross-wave reads in Phase C)

  // ---- Phase C: Head = P @ VfT^T (contraction over k in 4 staggered chunks) ----
  for (int i = 0; i < 4; ++i) {
    const int kc = (kc0 + i) & 3;
    stage_strip(Vfb, kc);
#pragma unroll
    for (int kk = 0; kk < 2; ++kk) {
      const int ko = kk * 32 + (lane >> 4) * 8;
      bf16x8 a[4], b[4];
#pragma unroll
      for (int m = 0; m < 4; ++m) {
        const int ar = m * 16 + (lane & 15);
        a[m] = *(const bf16x8*)((const char*)Qs +
                                ((ar * 512 + (kc * 64 + ko) * 2) ^ ((ar & 7) << 4)));
      }
#pragma unroll
      for (int n = 0; n < 4; ++n) {
        const int br = n * 16 + (lane & 15);
        b[n] = *(const bf16x8*)((const char*)Bst[w] + ((br * 128 + ko * 2) ^ ((br & 7) << 4)));
      }
#pragma unroll
      for (int m = 0; m < 4; ++m)
#pragma unroll
        for (int n = 0; n < 4; ++n)
          acc[m][n] = __builtin_amdgcn_mfma_f32_16x16x32_bf16(a[m], b[n], acc[m][n], 0, 0, 0);
    }
  }

  // ---- store f32 out ----
#pragma unroll
  for (int m = 0; m < 4; ++m)
#pragma unroll
    for (int n = 0; n < 4; ++n) {
      const long long row = R0 + m * 16 + r0;
      const int col = wc + n * 16 + c0;
#pragma unroll
      for (int j = 0; j < 4; ++j) out[(row + j) * 256 + col] = acc[m][n][j];
    }
}

extern "C" void kernel_launch(void* const* d_in, const int* in_sizes, int n_in, void* d_out,
                              int out_size, void* d_ws, size_t ws_size, hipStream_t stream) {
  (void)in_sizes; (void)n_in; (void)out_size; (void)ws_size;
  const float* I  = (const float*)d_in[0];
  const float* Wq = (const float*)d_in[1];
  const float* Wk = (const float*)d_in[2];
  const float* Wv = (const float*)d_in[3];
  const float* We = (const float*)d_in[4];
  const float* Wf = (const float*)d_in[5];
  float* out = (float*)d_out;
  char* ws = (char*)d_ws;

  u16* Ibf  = (u16*)(ws + 0);          // 16.8 MB [32768][256]
  u16* IT   = (u16*)(ws + 16777216);   // 16.8 MB [4][256][8192]
  u16* WqT  = (u16*)(ws + 33554432);   // 128 KB (transposed)
  u16* WkT  = (u16*)(ws + 33685504);   // 128 KB (transposed)
  u16* WvB  = (u16*)(ws + 33816576);   // 128 KB
  u16* WeB  = (u16*)(ws + 33947648);   // 4 MB
  u16* WfB  = (u16*)(ws + 38141952);   // 4 MB
  u16* G    = (u16*)(ws + 42336256);   // 128 KB
  float* Pp = (float*)(ws + 42467328); // 33.5 MB [8][16][65536]
  u16* SS   = (u16*)(ws + 76021760);   // 1 MB [8][65536] (Se b0..3, Sf b0..3)
  u16* Me   = (u16*)(ws + 77070336);   // 512 KB [4][256][256]
  u16* VfT  = (u16*)(ws + 77594624);   // 512 KB [4][256][256]

  k0<<<3120, 256, 0, stream>>>(I, Wq, Wk, Wv, We, Wf, Ibf, IT, WqT, WkT, WvB, WeB, WfB);
  k1<<<516, 256, 0, stream>>>(WqT, WkT, WeB, WfB, IT, Pp, G);
  reduce16<<<512, 256, 0, stream>>>(Pp, SS);
  k3<<<32, 256, 0, stream>>>(SS, G, WvB, Me, VfT);
  flash6<<<512, 256, 0, stream>>>(Ibf, Me, VfT, out);
}